// Round 11
// baseline (70548.651 us; speedup 1.0000x reference)
//
#include <hip/hip_runtime.h>
#include <math.h>

#define B_SZ 128
#define T_IN 8000
#define T_OUT 1600
#define HDIM 384
#define GDIM 1536   // 4*H
#define TC 40       // time chunk
#define NCHUNK (T_OUT / TC)   // 40
#define NTILES (12 * (B_SZ * TC / 128))   // 480 gemm tiles per chunk

typedef _Float16 f16;
typedef __attribute__((ext_vector_type(2))) _Float16 f16x2;
typedef __attribute__((ext_vector_type(4))) _Float16 f16x4;
typedef __attribute__((ext_vector_type(8))) _Float16 f16x8;

__device__ inline float fdot2(f16x2 a, f16x2 b, float c) {
#if __has_builtin(__builtin_amdgcn_fdot2)
  return __builtin_amdgcn_fdot2(a, b, c, false);
#else
  return fmaf((float)a[0], (float)b[0], fmaf((float)a[1], (float)b[1], c));
#endif
}

// ---------------------------------------------------------------------------
// conv1 (5,1,4) + silu + conv2 (5,4,16) + silu, fused. One thread per (b,t).
// ---------------------------------------------------------------------------
__global__ __launch_bounds__(256) void conv12_kernel(
    const float* __restrict__ x, const float* __restrict__ w1, const float* __restrict__ b1,
    const float* __restrict__ w2, const float* __restrict__ b2, f16* __restrict__ y2) {
  __shared__ float sw1[20], sb1[4], sw2[320], sb2[16];
  int tid = threadIdx.x;
  if (tid < 20) sw1[tid] = w1[tid];
  if (tid < 4)  sb1[tid] = b1[tid];
  if (tid < 16) sb2[tid] = b2[tid];
  for (int i = tid; i < 320; i += 256) sw2[i] = w2[i];
  __syncthreads();
  int flat = blockIdx.x * 256 + tid;
  int b = flat / T_IN, t = flat % T_IN;
  const float* xb = x + (size_t)b * T_IN;
  float xv[9];
#pragma unroll
  for (int d = 0; d < 9; ++d) {
    int tt = t + d - 4;
    xv[d] = (tt >= 0 && tt < T_IN) ? xb[tt] : 0.f;
  }
  float y1[5][4];
#pragma unroll
  for (int u = 0; u < 5; ++u) {
    int tau = t + u - 2;
    bool valid = (tau >= 0 && tau < T_IN);
#pragma unroll
    for (int co = 0; co < 4; ++co) {
      float a = sb1[co];
#pragma unroll
      for (int k = 0; k < 5; ++k) a = fmaf(xv[u + k], sw1[k * 4 + co], a);
      y1[u][co] = valid ? (a / (1.f + expf(-a))) : 0.f;
    }
  }
  f16x8 o0, o1;
#pragma unroll
  for (int co = 0; co < 16; ++co) {
    float a = sb2[co];
#pragma unroll
    for (int u = 0; u < 5; ++u)
#pragma unroll
      for (int ci = 0; ci < 4; ++ci)
        a = fmaf(y1[u][ci], sw2[(u * 4 + ci) * 16 + co], a);
    float sv = a / (1.f + expf(-a));
    if (co < 8) o0[co] = (f16)sv; else o1[co - 8] = (f16)sv;
  }
  f16x8* dst = (f16x8*)(y2 + (size_t)flat * 16);
  dst[0] = o0;
  dst[1] = o1;
}

// ---------------------------------------------------------------------------
// conv3: (19,16,384), stride 5, SAME (pad 7/7), + silu. fp16 in/out, fp32 math.
// ---------------------------------------------------------------------------
__global__ __launch_bounds__(384) void conv3_kernel(
    const f16* __restrict__ y2, const float* __restrict__ w3, const float* __restrict__ b3,
    f16* __restrict__ act) {
  __shared__ float in_s[94 * 16];
  int tid = threadIdx.x;
  int b = blockIdx.y;
  int t0 = blockIdx.x * 16;
  int base_t = t0 * 5 - 7;
  for (int i = tid; i < 94 * 16; i += 384) {
    int tau = i >> 4, ci = i & 15;
    int tt = base_t + tau;
    in_s[i] = (tt >= 0 && tt < T_IN) ? (float)y2[((size_t)b * T_IN + tt) * 16 + ci] : 0.f;
  }
  __syncthreads();
  int c = tid;
  float acc[16];
  float bv = b3[c];
#pragma unroll
  for (int tt = 0; tt < 16; ++tt) acc[tt] = bv;
  for (int kk = 0; kk < 19; ++kk) {
#pragma unroll
    for (int c4 = 0; c4 < 4; ++c4) {
      float wa = w3[(size_t)((kk * 16 + c4 * 4 + 0) * 384) + c];
      float wb = w3[(size_t)((kk * 16 + c4 * 4 + 1) * 384) + c];
      float wc = w3[(size_t)((kk * 16 + c4 * 4 + 2) * 384) + c];
      float wd = w3[(size_t)((kk * 16 + c4 * 4 + 3) * 384) + c];
#pragma unroll
      for (int tt = 0; tt < 16; ++tt) {
        const float4 iv = *(const float4*)&in_s[(tt * 5 + kk) * 16 + c4 * 4];
        acc[tt] = fmaf(iv.x, wa, acc[tt]);
        acc[tt] = fmaf(iv.y, wb, acc[tt]);
        acc[tt] = fmaf(iv.z, wc, acc[tt]);
        acc[tt] = fmaf(iv.w, wd, acc[tt]);
      }
    }
  }
#pragma unroll
  for (int tt = 0; tt < 16; ++tt) {
    float a = acc[tt];
    a = a / (1.f + expf(-a));
    act[((size_t)b * T_OUT + t0 + tt) * HDIM + c] = (f16)a;
  }
}

// ---------------------------------------------------------------------------
// Wh repack: whP[l][k2][c] = (Wh[l][2k2][c], Wh[l][2k2+1][c]) as fp16x2.
// ---------------------------------------------------------------------------
__global__ __launch_bounds__(256) void whcvt_kernel(
    const float* __restrict__ Wh, f16x2* __restrict__ whP) {
  size_t idx = (size_t)blockIdx.x * 256 + threadIdx.x;
  int l = (int)(idx / (192 * 1536));
  int rem = (int)(idx % (192 * 1536));
  int k2 = rem / 1536;
  int c = rem % 1536;
  const float* src = Wh + ((size_t)l * 384 + 2 * k2) * 1536 + c;
  f16x2 v;
  v[0] = (f16)src[0];
  v[1] = (f16)src[1536];
  whP[idx] = v;
}

// ---------------------------------------------------------------------------
// Standalone chunked xg GEMM (primes chunk 0 of each layer).
// ---------------------------------------------------------------------------
__global__ __launch_bounds__(256) void gemm_xg_kernel(
    const f16* __restrict__ act, const float* __restrict__ Bw,
    f16* __restrict__ C, int lo) {
  __shared__ f16x2 As2[8 * 136];
  __shared__ f16x2 Bs2[8 * 128];
  int tid = threadIdx.x;
  int n0 = blockIdx.x * 128;
  int m0 = blockIdx.y * 128;
  int am = tid >> 2;
  int ak = (tid & 3) * 4;
  int bk = tid >> 5;
  int bn = (tid & 31) * 4;
  int row0 = m0 + am, row1 = row0 + 64;
  const f16* Ap0 = act + ((size_t)(row0 / TC) * T_OUT + lo + row0 % TC) * HDIM + ak;
  const f16* Ap1 = act + ((size_t)(row1 / TC) * T_OUT + lo + row1 % TC) * HDIM + ak;
  const float* Bp = Bw + (size_t)(2 * bk) * GDIM + n0 + bn;
  f16x4 ra0 = *(const f16x4*)Ap0;
  f16x4 ra1 = *(const f16x4*)Ap1;
  float4 rb0 = *(const float4*)Bp;
  float4 rb1 = *(const float4*)(Bp + (size_t)GDIM);
  float acc[8][8];
#pragma unroll
  for (int i = 0; i < 8; ++i)
#pragma unroll
    for (int j = 0; j < 8; ++j) acc[i][j] = 0.f;
  int tx = tid & 15, ty = tid >> 4;
  for (int kt = 0; kt < 24; ++kt) {
    int ak2 = ak >> 1;
    As2[(ak2 + 0) * 136 + am] = (f16x2){ra0[0], ra0[1]};
    As2[(ak2 + 1) * 136 + am] = (f16x2){ra0[2], ra0[3]};
    As2[(ak2 + 0) * 136 + am + 64] = (f16x2){ra1[0], ra1[1]};
    As2[(ak2 + 1) * 136 + am + 64] = (f16x2){ra1[2], ra1[3]};
    Bs2[bk * 128 + bn + 0] = (f16x2){(f16)rb0.x, (f16)rb1.x};
    Bs2[bk * 128 + bn + 1] = (f16x2){(f16)rb0.y, (f16)rb1.y};
    Bs2[bk * 128 + bn + 2] = (f16x2){(f16)rb0.z, (f16)rb1.z};
    Bs2[bk * 128 + bn + 3] = (f16x2){(f16)rb0.w, (f16)rb1.w};
    __syncthreads();
    if (kt < 23) {
      Ap0 += 16; Ap1 += 16; Bp += (size_t)16 * GDIM;
      ra0 = *(const f16x4*)Ap0;
      ra1 = *(const f16x4*)Ap1;
      rb0 = *(const float4*)Bp;
      rb1 = *(const float4*)(Bp + (size_t)GDIM);
    }
#pragma unroll
    for (int k2 = 0; k2 < 8; ++k2) {
      f16x8 a0 = *(const f16x8*)&As2[k2 * 136 + ty * 4];
      f16x8 a1 = *(const f16x8*)&As2[k2 * 136 + 64 + ty * 4];
      f16x8 b0 = *(const f16x8*)&Bs2[k2 * 128 + tx * 4];
      f16x8 b1 = *(const f16x8*)&Bs2[k2 * 128 + 64 + tx * 4];
      f16x2 av[8], bv[8];
#pragma unroll
      for (int q = 0; q < 4; ++q) {
        av[q] = (f16x2){a0[2 * q], a0[2 * q + 1]};
        av[q + 4] = (f16x2){a1[2 * q], a1[2 * q + 1]};
        bv[q] = (f16x2){b0[2 * q], b0[2 * q + 1]};
        bv[q + 4] = (f16x2){b1[2 * q], b1[2 * q + 1]};
      }
#pragma unroll
      for (int i = 0; i < 8; ++i)
#pragma unroll
        for (int j = 0; j < 8; ++j) acc[i][j] = fdot2(av[i], bv[j], acc[i][j]);
    }
    __syncthreads();
  }
#pragma unroll
  for (int i = 0; i < 8; ++i) {
    int mi = (i < 4) ? (ty * 4 + i) : (64 + ty * 4 + i - 4);
    f16* Cp = C + (size_t)(m0 + mi) * GDIM + n0;
    f16x4 p0, p1;
    p0[0] = (f16)acc[i][0]; p0[1] = (f16)acc[i][1]; p0[2] = (f16)acc[i][2]; p0[3] = (f16)acc[i][3];
    p1[0] = (f16)acc[i][4]; p1[1] = (f16)acc[i][5]; p1[2] = (f16)acc[i][6]; p1[3] = (f16)acc[i][7];
    *(f16x4*)(Cp + tx * 4) = p0;
    *(f16x4*)(Cp + 64 + tx * 4) = p1;
  }
}

// ---------------------------------------------------------------------------
// FUSED kernel: 256 blocks x 768 threads.
//  blocks 0..63  : LSTM chunk at lo_l; 24/96 k2 of each thread's Wh slice
//                  PINNED in VGPRs via opaque asm (compiler cannot remat).
//  blocks 64..255: GEMM for next chunk at lo_g; 3 sub-tiles/block.
// ---------------------------------------------------------------------------
union FusedSh {
  struct { f16x2 h2s[2][192]; float zsp[2][2][1536]; float bias_s[1536]; } L;
  struct { f16x2 As2[3][8 * 136]; f16x2 Bs2[3][8 * 128]; } G;
  char pad[57344];
};

__global__ __launch_bounds__(768, 1) void fused_kernel(
    const f16* __restrict__ xgc_rd, f16* __restrict__ xgc_wr,
    const f16x2* __restrict__ whP, const float* __restrict__ bias,
    f16* __restrict__ act, float* __restrict__ cst, const float* __restrict__ Wi,
    int lo_l, int lo_g, int reverse, int first, int do_gemm) {
  __shared__ FusedSh sh;
  int tid = threadIdx.x;

  if (blockIdx.x < 64) {
    // ================= LSTM branch =================
    int wid = blockIdx.x;
    int b0 = wid * 2;
    for (int i = tid; i < 1536; i += 768) sh.L.bias_s[i] = bias[i];
    int bl = tid / 384;
    int j = tid - bl * 384;
    int kap = bl, cq = j;
    int c4 = 4 * cq;
    float c_st;
    if (first) {
      c_st = 0.f;
      ((f16*)sh.L.h2s)[tid] = (f16)0.f;
    } else {
      int tprev = reverse ? (lo_l + TC) : (lo_l - 1);
      c_st = cst[(size_t)(b0 + bl) * HDIM + j];
      ((f16*)&sh.L.h2s[bl][0])[j] = act[((size_t)(b0 + bl) * T_OUT + tprev) * HDIM + j];
    }

    const f16x2* wcol = whP + c4 + (size_t)(96 * kap) * 1536;
    const int k2base = 96 * kap;

    // VGPR weight cache: k2 rel [0,24) (96 VGPRs), pinned with opaque asm so
    // the compiler cannot rematerialize the loads inside the step loop.
    f16x8 wreg[6][4];
#pragma unroll
    for (int q = 0; q < 6; ++q)
#pragma unroll
      for (int r = 0; r < 4; ++r) {
        wreg[q][r] = *(const f16x8*)(wcol + (size_t)(4 * q + r) * 1536);
        asm volatile("" : "+v"(wreg[q][r]));
      }
    __syncthreads();

    for (int s = 0; s < TC; ++s) {
      int t = reverse ? (lo_l + TC - 1 - s) : (lo_l + s);
      int tl = t - lo_l;
      float a0[4] = {0.f, 0.f, 0.f, 0.f};
      float a1[4] = {0.f, 0.f, 0.f, 0.f};
      // --- cached section: k2 rel [0,24) ---
#pragma unroll
      for (int q = 0; q < 6; ++q) {
        int k2b = k2base + 4 * q;
        f16x8 ha = *(const f16x8*)&sh.L.h2s[0][k2b];
        f16x8 hb = *(const f16x8*)&sh.L.h2s[1][k2b];
        f16x2 ha0 = {ha[0], ha[1]}, ha1 = {ha[2], ha[3]}, ha2 = {ha[4], ha[5]}, ha3 = {ha[6], ha[7]};
        f16x2 hb0 = {hb[0], hb[1]}, hb1 = {hb[2], hb[3]}, hb2 = {hb[4], hb[5]}, hb3 = {hb[6], hb[7]};
#pragma unroll
        for (int c = 0; c < 4; ++c) {
          f16x2 wc0 = {wreg[q][0][2 * c], wreg[q][0][2 * c + 1]};
          f16x2 wc1 = {wreg[q][1][2 * c], wreg[q][1][2 * c + 1]};
          f16x2 wc2 = {wreg[q][2][2 * c], wreg[q][2][2 * c + 1]};
          f16x2 wc3 = {wreg[q][3][2 * c], wreg[q][3][2 * c + 1]};
          a0[c] = fdot2(wc0, ha0, a0[c]);
          a1[c] = fdot2(wc0, hb0, a1[c]);
          a0[c] = fdot2(wc1, ha1, a0[c]);
          a1[c] = fdot2(wc1, hb1, a1[c]);
          a0[c] = fdot2(wc2, ha2, a0[c]);
          a1[c] = fdot2(wc2, hb2, a1[c]);
          a0[c] = fdot2(wc3, ha3, a0[c]);
          a1[c] = fdot2(wc3, hb3, a1[c]);
        }
      }
      // --- streamed section: k2 rel [24,96) ---
      const f16x2* wp = wcol + (size_t)24 * 1536;
#pragma unroll 2
      for (int q = 6; q < 24; ++q) {
        int k2b = k2base + 4 * q;
        f16x8 w0 = *(const f16x8*)(wp);
        f16x8 w1 = *(const f16x8*)(wp + 1536);
        f16x8 w2 = *(const f16x8*)(wp + 2 * 1536);
        f16x8 w3 = *(const f16x8*)(wp + 3 * 1536);
        f16x8 ha = *(const f16x8*)&sh.L.h2s[0][k2b];
        f16x8 hb = *(const f16x8*)&sh.L.h2s[1][k2b];
        f16x2 ha0 = {ha[0], ha[1]}, ha1 = {ha[2], ha[3]}, ha2 = {ha[4], ha[5]}, ha3 = {ha[6], ha[7]};
        f16x2 hb0 = {hb[0], hb[1]}, hb1 = {hb[2], hb[3]}, hb2 = {hb[4], hb[5]}, hb3 = {hb[6], hb[7]};
#pragma unroll
        for (int c = 0; c < 4; ++c) {
          f16x2 wc0 = {w0[2 * c], w0[2 * c + 1]};
          f16x2 wc1 = {w1[2 * c], w1[2 * c + 1]};
          f16x2 wc2 = {w2[2 * c], w2[2 * c + 1]};
          f16x2 wc3 = {w3[2 * c], w3[2 * c + 1]};
          a0[c] = fdot2(wc0, ha0, a0[c]);
          a1[c] = fdot2(wc0, hb0, a1[c]);
          a0[c] = fdot2(wc1, ha1, a0[c]);
          a1[c] = fdot2(wc1, hb1, a1[c]);
          a0[c] = fdot2(wc2, ha2, a0[c]);
          a1[c] = fdot2(wc2, hb2, a1[c]);
          a0[c] = fdot2(wc3, ha3, a0[c]);
          a1[c] = fdot2(wc3, hb3, a1[c]);
        }
        wp += 4 * 1536;
      }
      *(float4*)&sh.L.zsp[kap][0][c4] = make_float4(a0[0], a0[1], a0[2], a0[3]);
      *(float4*)&sh.L.zsp[kap][1][c4] = make_float4(a1[0], a1[1], a1[2], a1[3]);
      __syncthreads();
      {
        float zi = sh.L.zsp[0][bl][j]        + sh.L.zsp[1][bl][j]        + sh.L.bias_s[j];
        float zf = sh.L.zsp[0][bl][384 + j]  + sh.L.zsp[1][bl][384 + j]  + sh.L.bias_s[384 + j];
        float zg = sh.L.zsp[0][bl][768 + j]  + sh.L.zsp[1][bl][768 + j]  + sh.L.bias_s[768 + j];
        float zo = sh.L.zsp[0][bl][1152 + j] + sh.L.zsp[1][bl][1152 + j] + sh.L.bias_s[1152 + j];
        const f16* xp = xgc_rd + ((size_t)(b0 + bl) * TC + tl) * GDIM + j;
        zi += (float)xp[0];
        zf += (float)xp[384];
        zg += (float)xp[768];
        zo += (float)xp[1152];
        float ig = 1.f / (1.f + expf(-zi));
        float fg = 1.f / (1.f + expf(-zf));
        float gv = tanhf(zg);
        float og = 1.f / (1.f + expf(-zo));
        c_st = fg * c_st + ig * gv;
        float hv = og * tanhf(c_st);
        f16 h16v = (f16)hv;
        ((f16*)&sh.L.h2s[bl][0])[j] = h16v;
        act[((size_t)(b0 + bl) * T_OUT + t) * HDIM + j] = h16v;
      }
      __syncthreads();
    }
    cst[(size_t)(b0 + bl) * HDIM + j] = c_st;
  } else {
    // ================= GEMM worker branch =================
    if (!do_gemm) return;
    int wid = blockIdx.x - 64;        // 0..191
    int sub = tid >> 8;               // 0..2 (wave-uniform)
    int stid = tid & 255;
    int tileid = wid + 192 * sub;     // 0..575
    bool valid = (tileid < NTILES);
    int tclamp = valid ? tileid : 0;
    int n0 = (tclamp % 12) * 128;
    int m0 = (tclamp / 12) * 128;
    f16x2* As2 = &sh.G.As2[sub][0];
    f16x2* Bs2 = &sh.G.Bs2[sub][0];
    int am = stid >> 2;
    int ak = (stid & 3) * 4;
    int bk = stid >> 5;
    int bn = (stid & 31) * 4;
    int row0 = m0 + am, row1 = row0 + 64;
    const f16* Ap0 = act + ((size_t)(row0 / TC) * T_OUT + lo_g + row0 % TC) * HDIM + ak;
    const f16* Ap1 = act + ((size_t)(row1 / TC) * T_OUT + lo_g + row1 % TC) * HDIM + ak;
    const float* Bp = Wi + (size_t)(2 * bk) * GDIM + n0 + bn;
    f16x4 ra0 = {}, ra1 = {};
    float4 rb0 = {}, rb1 = {};
    if (valid) {
      ra0 = *(const f16x4*)Ap0;
      ra1 = *(const f16x4*)Ap1;
      rb0 = *(const float4*)Bp;
      rb1 = *(const float4*)(Bp + (size_t)GDIM);
    }
    float acc[8][8];
#pragma unroll
    for (int i = 0; i < 8; ++i)
#pragma unroll
      for (int j = 0; j < 8; ++j) acc[i][j] = 0.f;
    int tx = stid & 15, ty = stid >> 4;
    for (int kt = 0; kt < 24; ++kt) {
      if (valid) {
        int ak2 = ak >> 1;
        As2[(ak2 + 0) * 136 + am] = (f16x2){ra0[0], ra0[1]};
        As2[(ak2 + 1) * 136 + am] = (f16x2){ra0[2], ra0[3]};
        As2[(ak2 + 0) * 136 + am + 64] = (f16x2){ra1[0], ra1[1]};
        As2[(ak2 + 1) * 136 + am + 64] = (f16x2){ra1[2], ra1[3]};
        Bs2[bk * 128 + bn + 0] = (f16x2){(f16)rb0.x, (f16)rb1.x};
        Bs2[bk * 128 + bn + 1] = (f16x2){(f16)rb0.y, (f16)rb1.y};
        Bs2[bk * 128 + bn + 2] = (f16x2){(f16)rb0.z, (f16)rb1.z};
        Bs2[bk * 128 + bn + 3] = (f16x2){(f16)rb0.w, (f16)rb1.w};
      }
      __syncthreads();
      if (valid) {
        if (kt < 23) {
          Ap0 += 16; Ap1 += 16; Bp += (size_t)16 * GDIM;
          ra0 = *(const f16x4*)Ap0;
          ra1 = *(const f16x4*)Ap1;
          rb0 = *(const float4*)Bp;
          rb1 = *(const float4*)(Bp + (size_t)GDIM);
        }
#pragma unroll
        for (int k2 = 0; k2 < 8; ++k2) {
          f16x8 a0 = *(const f16x8*)&As2[k2 * 136 + ty * 4];
          f16x8 a1 = *(const f16x8*)&As2[k2 * 136 + 64 + ty * 4];
          f16x8 b0 = *(const f16x8*)&Bs2[k2 * 128 + tx * 4];
          f16x8 b1 = *(const f16x8*)&Bs2[k2 * 128 + 64 + tx * 4];
          f16x2 av[8], bv[8];
#pragma unroll
          for (int q = 0; q < 4; ++q) {
            av[q] = (f16x2){a0[2 * q], a0[2 * q + 1]};
            av[q + 4] = (f16x2){a1[2 * q], a1[2 * q + 1]};
            bv[q] = (f16x2){b0[2 * q], b0[2 * q + 1]};
            bv[q + 4] = (f16x2){b1[2 * q], b1[2 * q + 1]};
          }
#pragma unroll
          for (int i = 0; i < 8; ++i)
#pragma unroll
            for (int j = 0; j < 8; ++j) acc[i][j] = fdot2(av[i], bv[j], acc[i][j]);
        }
      }
      __syncthreads();
    }
    if (valid) {
#pragma unroll
      for (int i = 0; i < 8; ++i) {
        int mi = (i < 4) ? (ty * 4 + i) : (64 + ty * 4 + i - 4);
        f16* Cp = xgc_wr + (size_t)(m0 + mi) * GDIM + n0;
        f16x4 p0, p1;
        p0[0] = (f16)acc[i][0]; p0[1] = (f16)acc[i][1]; p0[2] = (f16)acc[i][2]; p0[3] = (f16)acc[i][3];
        p1[0] = (f16)acc[i][4]; p1[1] = (f16)acc[i][5]; p1[2] = (f16)acc[i][6]; p1[3] = (f16)acc[i][7];
        *(f16x4*)(Cp + tx * 4) = p0;
        *(f16x4*)(Cp + 64 + tx * 4) = p1;
      }
    }
  }
}

// ---------------------------------------------------------------------------
// dense: out(204800,5) = h(204800,384 fp16) @ W(384,5) + b  (fp32 out)
// ---------------------------------------------------------------------------
__global__ __launch_bounds__(256) void dense_kernel(
    const f16* __restrict__ h, const float* __restrict__ dw,
    const float* __restrict__ db, float* __restrict__ out) {
  __shared__ float ws_[1920];
  __shared__ float bs[5];
  int tid = threadIdx.x;
  for (int i = tid; i < 1920; i += 256) ws_[i] = dw[i];
  if (tid < 5) bs[tid] = db[tid];
  __syncthreads();
  size_t flat = (size_t)blockIdx.x * 256 + tid;
  const f16* hp = h + flat * HDIM;
  float acc[5];
#pragma unroll
  for (int o = 0; o < 5; ++o) acc[o] = bs[o];
  for (int d = 0; d < HDIM; d += 4) {
    f16x4 hv = *(const f16x4*)(hp + d);
#pragma unroll
    for (int o = 0; o < 5; ++o) {
      acc[o] = fmaf((float)hv[0], ws_[(d + 0) * 5 + o], acc[o]);
      acc[o] = fmaf((float)hv[1], ws_[(d + 1) * 5 + o], acc[o]);
      acc[o] = fmaf((float)hv[2], ws_[(d + 2) * 5 + o], acc[o]);
      acc[o] = fmaf((float)hv[3], ws_[(d + 3) * 5 + o], acc[o]);
    }
  }
  float* op = out + flat * 5;
#pragma unroll
  for (int o = 0; o < 5; ++o) op[o] = acc[o];
}

// ---------------------------------------------------------------------------
extern "C" void kernel_launch(void* const* d_in, const int* in_sizes, int n_in,
                              void* d_out, int out_size, void* d_ws, size_t ws_size,
                              hipStream_t stream) {
  const float* x  = (const float*)d_in[0];
  const float* w1 = (const float*)d_in[1];
  const float* b1 = (const float*)d_in[2];
  const float* w2 = (const float*)d_in[3];
  const float* b2 = (const float*)d_in[4];
  const float* w3 = (const float*)d_in[5];
  const float* b3 = (const float*)d_in[6];
  const float* Wi = (const float*)d_in[7];
  const float* Wh = (const float*)d_in[8];
  const float* lb = (const float*)d_in[9];
  const float* dw = (const float*)d_in[10];
  const float* db = (const float*)d_in[11];
  float* out = (float*)d_out;
  char* ws = (char*)d_ws;

  // ws (~194.8 MB <= proven 197): act | xgcA | xgcB | whP | cst
  const size_t ACT_BYTES = (size_t)B_SZ * T_OUT * HDIM * 2;   // 157.3 MB
  const size_t XGC_BYTES = (size_t)B_SZ * TC * GDIM * 2;      // 15.7 MB each
  const size_t WHP_BYTES = (size_t)5 * 192 * 1536 * 4;        // 5.9 MB
  f16*   act  = (f16*)ws;
  f16*   xgcA = (f16*)(ws + ACT_BYTES);
  f16*   xgcB = (f16*)(ws + ACT_BYTES + XGC_BYTES);
  f16x2* whP  = (f16x2*)(ws + ACT_BYTES + 2 * XGC_BYTES);
  float* cst  = (float*)(ws + ACT_BYTES + 2 * XGC_BYTES + WHP_BYTES);
  f16* y2 = xgcA;  // alias: consumed before xgc/whP are written

  hipLaunchKernelGGL(conv12_kernel, dim3(B_SZ * T_IN / 256), dim3(256), 0, stream,
                     x, w1, b1, w2, b2, y2);
  hipLaunchKernelGGL(conv3_kernel, dim3(T_OUT / 16, B_SZ), dim3(384), 0, stream,
                     y2, w3, b3, act);
  hipLaunchKernelGGL(whcvt_kernel, dim3(5 * 192 * 1536 / 256), dim3(256), 0, stream,
                     Wh, whP);

  for (int l = 0; l < 5; ++l) {
    int rev = (l % 2 == 0) ? 1 : 0;
    const float* wi_p = Wi + (size_t)l * HDIM * GDIM;
    const f16x2* wh_p = whP + (size_t)l * 192 * 1536;
    const float* lb_p = lb + (size_t)l * GDIM;
    int lo0 = rev ? (T_OUT - TC) : 0;
    hipLaunchKernelGGL(gemm_xg_kernel, dim3(GDIM / 128, (B_SZ * TC) / 128), dim3(256), 0, stream,
                       act, wi_p, xgcA, lo0);
    for (int ci = 0; ci < NCHUNK; ++ci) {
      int lo_l = rev ? (T_OUT - (ci + 1) * TC) : (ci * TC);
      int do_gemm = (ci + 1 < NCHUNK) ? 1 : 0;
      int lo_g = do_gemm ? (rev ? (T_OUT - (ci + 2) * TC) : ((ci + 1) * TC)) : 0;
      f16* rd = (ci % 2 == 0) ? xgcA : xgcB;
      f16* wr = (ci % 2 == 0) ? xgcB : xgcA;
      hipLaunchKernelGGL(fused_kernel, dim3(256), dim3(768), 0, stream,
                         rd, wr, wh_p, lb_p, act, cst, wi_p,
                         lo_l, lo_g, rev, (ci == 0) ? 1 : 0, do_gemm);
    }
  }
  hipLaunchKernelGGL(dense_kernel, dim3((B_SZ * T_OUT) / 256), dim3(256), 0, stream,
                     act, dw, db, out);
}